// Round 5
// baseline (57.017 us; speedup 1.0000x reference)
//
#include <hip/hip_runtime.h>
#include <hip/hip_cooperative_groups.h>
#include <math.h>

namespace cg = cooperative_groups;

// heatmap [64,17,128,128] f32, targets [64,17,3] f32 (x, y, visible)
constexpr int Hc   = 128;
constexpr int Wc   = 128;
constexpr int HWc  = Hc * Wc;        // 16384
constexpr int NBK  = 64 * 17;        // 1088
constexpr int RPB  = 4;              // (b,k) rows per block
constexpr int NBLK = NBK / RPB;      // 272 blocks, all co-resident

constexpr float E2_1 = 0.13533528323661270f;               // e^-2
constexpr float E2_4 = 3.3546262790251185e-4f;             // e^-8
constexpr float S1F  = 1.0f + 2.0f * E2_1 + 2.0f * E2_4;   // 1D kernel sum
constexpr float INVN = 1.0f / (S1F * S1F);                 // 1/k2.sum()

__device__ __forceinline__ float gfac(int d) {   // e^{-2 d^2}, |d|<=2
    const int a = d < 0 ? -d : d;
    return a == 0 ? 1.0f : (a == 1 ? E2_1 : E2_4);
}

// Single cooperative kernel.
// Phase 1: quarter-block (4 waves, 256 threads) per (b,k) row:
//   stream 16 KB -> sum(exp(x)) (no max; inputs O(1), f32 ample),
//   25 lanes gather the Gaussian window (L1-resident), closed-form window
//   constants, per-row loss -> per-block sum -> part[blk].
// grid.sync()
// Phase 2: block 0 reduces 272 partials + n_vis from targets, writes loss.
__global__ __launch_bounds__(1024, 8) void kl_all(const float* __restrict__ hm,
                                                  const float* __restrict__ tg,
                                                  float* __restrict__ part,
                                                  float* __restrict__ out) {
    const int blk     = blockIdx.x;
    const int tid     = threadIdx.x;
    const int row     = tid >> 8;          // 0..3
    const int lane256 = tid & 255;
    const int bk      = blk * RPB + row;
    const int wave    = tid >> 6;          // 0..15

    const float4* __restrict__ base4 =
        reinterpret_cast<const float4*>(hm + (size_t)bk * HWc);

    // ---- streaming exp-sum over this row's 4096 float4s (16 per thread) ----
    float s0 = 0.f, s1 = 0.f, s2 = 0.f, s3 = 0.f;
#pragma unroll 4
    for (int c = 0; c < 16; ++c) {
        const float4 v = base4[c * 256 + lane256];
        s0 += __expf(v.x); s1 += __expf(v.y);
        s2 += __expf(v.z); s3 += __expf(v.w);
    }
    float s = (s0 + s1) + (s2 + s3);

    // ---- Gaussian-window dot product: lanes 0..24 of the row's first wave ----
    float gh = 0.f;
    if (lane256 < 25) {
        const int dy = lane256 / 5 - 2;
        const int dx = lane256 % 5 - 2;
        const int tx = __float2int_rn(tg[bk * 3 + 0]) + dx;
        const int ty = __float2int_rn(tg[bk * 3 + 1]) + dy;
        if (tx >= 0 && tx < Wc && ty >= 0 && ty < Hc)
            gh = gfac(dx) * gfac(dy) * INVN * hm[(size_t)bk * HWc + ty * Wc + tx];
    }

#pragma unroll
    for (int off = 32; off; off >>= 1) s += __shfl_xor(s, off);
#pragma unroll
    for (int off = 16; off; off >>= 1) gh += __shfl_xor(gh, off);  // lanes 0..31

    __shared__ float ss[16];
    __shared__ float rowres[RPB];
    if ((tid & 63) == 0) ss[wave] = s;
    __syncthreads();

    if (lane256 == 0) {   // row leader (tid = 256*row); holds reduced gh
        const float S   = ss[4 * row] + ss[4 * row + 1] + ss[4 * row + 2] + ss[4 * row + 3];
        const float lse = __logf(S);

        const int tx  = __float2int_rn(tg[bk * 3 + 0]);
        const int ty  = __float2int_rn(tg[bk * 3 + 1]);
        const int vis = __float2int_rn(tg[bk * 3 + 2]) > 0;

        const float LOGN = 2.0f * __logf(S1F);
        float cgs = 0.f, cglg = 0.f;
#pragma unroll
        for (int w = 0; w < 25; ++w) {
            const int dy = w / 5 - 2;
            const int dx = w % 5 - 2;
            const int x = tx + dx, y = ty + dy;
            if (x >= 0 && x < Wc && y >= 0 && y < Hc) {
                const float g = gfac(dx) * gfac(dy) * INVN;
                cgs  += g;
                cglg += g * (-2.f * (float)(dx * dx + dy * dy) - LOGN);
            }
        }
        rowres[row] = vis ? (cglg - gh + lse * cgs) : 0.f;
    }
    __syncthreads();
    if (tid == 0)
        part[blk] = (rowres[0] + rowres[1]) + (rowres[2] + rowres[3]);

    // ---- grid-wide barrier, then block 0 finishes ----
    cg::this_grid().sync();
    if (blk != 0) return;

    float a  = (tid < NBLK) ? part[tid] : 0.f;
    float nv = (tid < NBK && __float2int_rn(tg[3 * tid + 2]) > 0) ? 1.f : 0.f;
    if (tid < NBK - 1024)
        nv += (__float2int_rn(tg[3 * (tid + 1024) + 2]) > 0) ? 1.f : 0.f;

#pragma unroll
    for (int off = 32; off; off >>= 1) {
        a  += __shfl_xor(a,  off);
        nv += __shfl_xor(nv, off);
    }
    __shared__ float sa[16], sn[16];
    if ((tid & 63) == 0) { sa[wave] = a; sn[wave] = nv; }
    __syncthreads();
    if (tid == 0) {
        a = 0.f; nv = 0.f;
#pragma unroll
        for (int w = 0; w < 16; ++w) { a += sa[w]; nv += sn[w]; }
        out[0] = a / fmaxf(nv, 1.f);
    }
}

extern "C" void kernel_launch(void* const* d_in, const int* in_sizes, int n_in,
                              void* d_out, int out_size, void* d_ws, size_t ws_size,
                              hipStream_t stream) {
    const float* heatmap = (const float*)d_in[0];
    const float* targets = (const float*)d_in[1];
    float* part = (float*)d_ws;
    float* out  = (float*)d_out;

    void* args[] = {(void*)&heatmap, (void*)&targets, (void*)&part, (void*)&out};
    hipLaunchCooperativeKernel((const void*)kl_all, dim3(NBLK), dim3(1024),
                               args, 0, stream);
}

// Round 6
// 19.931 us; speedup vs baseline: 2.8608x; 2.8608x over previous
//
#include <hip/hip_runtime.h>
#include <math.h>

// heatmap [64,17,128,128] f32, targets [64,17,3] f32 (x, y, visible)
constexpr int Hc   = 128;
constexpr int Wc   = 128;
constexpr int HWc  = Hc * Wc;          // 16384
constexpr int NBK  = 64 * 17;          // 1088
constexpr int NSEG = NBK * 8;          // eighth-rows: 2048 elems each
constexpr int NBLK = NSEG / 4;         // 2176 blocks x 4 waves

constexpr float E2_1 = 0.13533528323661270f;               // e^-2
constexpr float E2_4 = 3.3546262790251185e-4f;             // e^-8
constexpr float S1F  = 1.0f + 2.0f * E2_1 + 2.0f * E2_4;   // 1D kernel sum
constexpr float INVN = 1.0f / (S1F * S1F);                 // 1/k2.sum()

__device__ __forceinline__ float gfac(int d) {   // e^{-2 d^2}, |d|<=2
    const int a = d < 0 ? -d : d;
    return a == 0 ? 1.0f : (a == 1 ? E2_1 : E2_4);
}

// Kernel 1: one WAVE per eighth-row (2048 elems = 16 image rows).
// No LDS, no __syncthreads — each wave streams 8 float4/lane (all 8 loads
// issued before any exp: max memory-level parallelism), reduces via shuffles,
// writes (expsum, gh) partials.
__global__ __launch_bounds__(256) void kl_pass(const float* __restrict__ hm,
                                               const float* __restrict__ tg,
                                               float* __restrict__ part) {
    const int tid  = threadIdx.x;
    const int lane = tid & 63;
    const int seg  = blockIdx.x * 4 + (tid >> 6);   // global eighth-row id
    const int bk   = seg >> 3;
    const int e8   = seg & 7;

    const float4* __restrict__ base4 =
        reinterpret_cast<const float4*>(hm + (size_t)bk * HWc + e8 * 2048);

    float4 v[8];
#pragma unroll
    for (int c = 0; c < 8; ++c) v[c] = base4[c * 64 + lane];

    float s0 = 0.f, s1 = 0.f, s2 = 0.f, s3 = 0.f;
#pragma unroll
    for (int c = 0; c < 8; ++c) {
        s0 += __expf(v[c].x); s1 += __expf(v[c].y);
        s2 += __expf(v[c].z); s3 += __expf(v[c].w);
    }
    float s = (s0 + s1) + (s2 + s3);

    // Gaussian-window partial: this eighth covers image rows [e8*16, e8*16+16)
    float gh = 0.f;
    if (lane < 25) {
        const int dy = lane / 5 - 2;
        const int dx = lane % 5 - 2;
        const int tx = __float2int_rn(tg[bk * 3 + 0]) + dx;
        const int ty = __float2int_rn(tg[bk * 3 + 1]) + dy;
        const int r0 = e8 * 16;
        if (tx >= 0 && tx < Wc && ty >= r0 && ty < r0 + 16)
            gh = gfac(dx) * gfac(dy) * INVN * hm[(size_t)bk * HWc + ty * Wc + tx];
    }

#pragma unroll
    for (int off = 32; off; off >>= 1) {
        s  += __shfl_xor(s,  off);
        gh += __shfl_xor(gh, off);
    }
    if (lane == 0) {
        part[seg]        = s;
        part[NSEG + seg] = gh;
    }
}

// Kernel 2: single 1024-thread block. Per bk: combine 8 partials -> lse,
// closed-form window constants, vis-weighted batchmean.
__global__ __launch_bounds__(1024) void kl_final(const float* __restrict__ part,
                                                 const float* __restrict__ tg,
                                                 float* __restrict__ out) {
    const int tid = threadIdx.x;
    const float LOGN = 2.0f * __logf(S1F);   // log(k2.sum())

    float acc = 0.f, nv = 0.f;
    for (int i = tid; i < NBK; i += 1024) {
        const float4 sa0 = *reinterpret_cast<const float4*>(part + 8 * i);
        const float4 sa1 = *reinterpret_cast<const float4*>(part + 8 * i + 4);
        const float4 ga0 = *reinterpret_cast<const float4*>(part + NSEG + 8 * i);
        const float4 ga1 = *reinterpret_cast<const float4*>(part + NSEG + 8 * i + 4);
        const float S  = ((sa0.x + sa0.y) + (sa0.z + sa0.w)) +
                         ((sa1.x + sa1.y) + (sa1.z + sa1.w));
        const float gh = ((ga0.x + ga0.y) + (ga0.z + ga0.w)) +
                         ((ga1.x + ga1.y) + (ga1.z + ga1.w));
        const float lse = __logf(S);

        const int tx  = __float2int_rn(tg[3 * i + 0]);
        const int ty  = __float2int_rn(tg[3 * i + 1]);
        const int vis = __float2int_rn(tg[3 * i + 2]) > 0;

        float cg = 0.f, cglg = 0.f;
#pragma unroll
        for (int w = 0; w < 25; ++w) {
            const int dy = w / 5 - 2;
            const int dx = w % 5 - 2;
            const int x = tx + dx, y = ty + dy;
            if (x >= 0 && x < Wc && y >= 0 && y < Hc) {
                const float g = gfac(dx) * gfac(dy) * INVN;
                cg   += g;
                cglg += g * (-2.f * (float)(dx * dx + dy * dy) - LOGN);
            }
        }
        const float per = cglg - gh + lse * cg;
        acc += vis ? per : 0.f;
        nv  += vis ? 1.f : 0.f;
    }

#pragma unroll
    for (int off = 32; off; off >>= 1) {
        acc += __shfl_xor(acc, off);
        nv  += __shfl_xor(nv,  off);
    }
    __shared__ float sa[16], sn[16];
    const int wave = tid >> 6;
    if ((tid & 63) == 0) { sa[wave] = acc; sn[wave] = nv; }
    __syncthreads();
    if (tid == 0) {
        float a = 0.f, n = 0.f;
#pragma unroll
        for (int w = 0; w < 16; ++w) { a += sa[w]; n += sn[w]; }
        out[0] = a / fmaxf(n, 1.f);
    }
}

extern "C" void kernel_launch(void* const* d_in, const int* in_sizes, int n_in,
                              void* d_out, int out_size, void* d_ws, size_t ws_size,
                              hipStream_t stream) {
    const float* heatmap = (const float*)d_in[0];
    const float* targets = (const float*)d_in[1];
    float* part = (float*)d_ws;
    float* out  = (float*)d_out;

    kl_pass<<<NBLK, 256, 0, stream>>>(heatmap, targets, part);
    kl_final<<<1, 1024, 0, stream>>>(part, targets, out);
}